// Round 16
// baseline (57.262 us; speedup 1.0000x reference)
//
#include <hip/hip_runtime.h>
#include <hip/hip_bf16.h>
#include <math.h>

typedef float f32x4 __attribute__((ext_vector_type(4)));
typedef short s16x8 __attribute__((ext_vector_type(8)));

#define KKW 49
#define HWTOT 1024
#define CIN 512
#define COUT 512

// ws float offsets (x1t/x2t/x3t regions hold bf16)
#define OFF_X1T 0
#define OFF_X2T 262144
#define OFF_X3T 524288
#define OFF_PM  2621440
#define OFF_A0  2623488
#define OFF_C0  2623554
#define OFF_W64 2623620
#define OFF_W65 2623684
#define OFF_C1V 2623748
#define OFF_W1B 2623812   /* 4096 bf16 (a1-folded wcw1[:, :64]) */
#define OFF_W2B 2625860   /* reserved */
#define OFF_W2F 2627908   /* 4096 bf16 (wcw2^T pre-fragmented for GEMM2 B) */
#define OFF_WT  2629956   /* 640x512 bf16, 5x8 tiles of [128m][64k] swizzled */
#define OFF_XT  2793796   /* 4x1024x512 bf16, 4x8x8 tiles of [128n][64k] swizzled */
#define WS_NEED_FLOATS 3842372ull

#define SWZ(bb)  ((bb) ^ ((((bb) >> 7) & 7) << 4))

#define GLD16(g, l) __builtin_amdgcn_global_load_lds( \
    (const __attribute__((address_space(1))) void*)(g), \
    (__attribute__((address_space(3))) void*)(l), 16, 0, 0)

__device__ __forceinline__ int refl(int m) {
    if (m < 0) m = -m;
    if (m > 31) m = 62 - m;
    return m;
}

__device__ __forceinline__ unsigned short fbf(float f) {
    unsigned u = __builtin_bit_cast(unsigned, f);
    unsigned r = u + 0x7fffu + ((u >> 16) & 1u);
    return (unsigned short)(r >> 16);
}

__device__ __forceinline__ unsigned pk2bf(float a, float b) {
    float2 f2; f2.x = a; f2.y = b;
    __hip_bfloat162 h = __float22bfloat162_rn(f2);
    union { __hip_bfloat162 h2; unsigned u; } cv;
    cv.h2 = h;
    return cv.u;
}

__device__ __forceinline__ float bf2f(unsigned short u) {
    unsigned v = (unsigned)u << 16;
    return __builtin_bit_cast(float, v);
}

__device__ __forceinline__ void setup_body(
        int tid,
        const float* __restrict__ wp, const float* __restrict__ bp,
        const float* __restrict__ g0, const float* __restrict__ be0,
        const float* __restrict__ m0, const float* __restrict__ v0,
        const float* __restrict__ wcw1,
        const float* __restrict__ g1, const float* __restrict__ be1,
        const float* __restrict__ m1, const float* __restrict__ v1,
        const float* __restrict__ wcw2,
        float* __restrict__ ws) {
    float* pm = ws + OFF_PM;
    for (int n = tid; n < HWTOT; n += 256) {
        int xx = n & 31, yy = n >> 5;
        float lw = -1.f + (2.f / 31.f) * xx;
        float lh = -1.f + (2.f / 31.f) * yy;
        pm[n * 2 + 0] = wp[0] * lw + wp[1] * lh + bp[0];
        pm[n * 2 + 1] = wp[2] * lw + wp[3] * lh + bp[1];
    }
    if (tid < 66) {
        float a = g0[tid] * rsqrtf(v0[tid] + 1e-5f);
        ws[OFF_A0 + tid] = a;
        ws[OFF_C0 + tid] = be0[tid] - m0[tid] * a;
    }
    if (tid < 64) {
        float a1c = g1[tid] * rsqrtf(v1[tid] + 1e-5f);
        ws[OFF_W64 + tid] = a1c * wcw1[tid * 66 + 64];
        ws[OFF_W65 + tid] = a1c * wcw1[tid * 66 + 65];
        ws[OFF_C1V + tid] = be1[tid] - m1[tid] * a1c;
    }
    unsigned short* w1b = (unsigned short*)(ws + OFF_W1B);
    unsigned short* w2f = (unsigned short*)(ws + OFF_W2F);
    for (int t = tid; t < 4096; t += 256) {
        int co = t >> 6, r = t & 63;
        float a1c = g1[co] * rsqrtf(v1[co] + 1e-5f);
        w1b[t] = fbf(a1c * wcw1[co * 66 + r]);
        int j = t & 7, idx = t >> 3;
        int ft = idx >> 6, l = idx & 63;
        int gt = ft >> 1, ks2 = ft & 1;
        int g = (l & 15) + gt * 16;
        int c2 = ks2 * 32 + (l >> 4) * 8 + j;
        w2f[t] = fbf(wcw2[g * 64 + c2]);
    }
}

__global__ void k_setup(const float* __restrict__ wp, const float* __restrict__ bp,
                        const float* __restrict__ g0, const float* __restrict__ be0,
                        const float* __restrict__ m0, const float* __restrict__ v0,
                        const float* __restrict__ wcw1,
                        const float* __restrict__ g1, const float* __restrict__ be1,
                        const float* __restrict__ m1, const float* __restrict__ v1,
                        const float* __restrict__ wcw2,
                        float* __restrict__ ws) {
    setup_body(threadIdx.x, wp, bp, g0, be0, m0, v0, wcw1, g1, be1, m1, v1, wcw2, ws);
}

// Pack weights (blocks 0..39), x-transpose (blocks 40..295), setup (block 296).
__global__ __launch_bounds__(256) void k_prep(
        const float* __restrict__ x,
        const float* __restrict__ w1, const float* __restrict__ w2,
        const float* __restrict__ w3,
        const float* __restrict__ wp, const float* __restrict__ bp,
        const float* __restrict__ g0, const float* __restrict__ be0,
        const float* __restrict__ m0, const float* __restrict__ v0,
        const float* __restrict__ wcw1,
        const float* __restrict__ g1, const float* __restrict__ be1,
        const float* __restrict__ m1, const float* __restrict__ v1,
        const float* __restrict__ wcw2,
        float* __restrict__ ws) {
    int bid = blockIdx.x;
    int tid = threadIdx.x;
    if (bid == 296) {
        setup_body(tid, wp, bp, g0, be0, m0, v0, wcw1, g1, be1, m1, v1, wcw2, ws);
    } else if (bid < 40) {
        int mT = bid / 8, kT = bid % 8;
        char* dst = (char*)(ws + OFF_WT) + (mT * 8 + kT) * 16384;
#pragma unroll
        for (int it = 0; it < 4; ++it) {
            int item = it * 256 + tid;
            int m = item >> 3, k8 = item & 7;
            int mg = mT * 128 + m;
            const float* src;
            if (mg < 64) src = w1 + mg * CIN;
            else if (mg < 128) src = w2 + (mg - 64) * CIN;
            else src = w3 + (mg - 128) * CIN;
            int k0 = kT * 64 + k8 * 8;
            s16x8 h;
#pragma unroll
            for (int i = 0; i < 8; i++) h[i] = (short)fbf(src[k0 + i]);
            *(s16x8*)(dst + SWZ(m * 128 + k8 * 16)) = h;
        }
    } else {
        __shared__ float lds[64 * 129];
        int t = bid - 40;  // b(4) nT(8) kT(8)
        int b = t >> 6, nT = (t >> 3) & 7, kT = t & 7;
        const float* src = x + (b * CIN + kT * 64) * HWTOT + nT * 128;
#pragma unroll
        for (int it = 0; it < 8; ++it) {
            int item = it * 256 + tid;
            int kk = item >> 5, n4 = item & 31;
            float4 v = *(const float4*)(src + kk * HWTOT + n4 * 4);
            float* d = &lds[kk * 129 + n4 * 4];
            d[0] = v.x; d[1] = v.y; d[2] = v.z; d[3] = v.w;
        }
        __syncthreads();
        char* dst = (char*)(ws + OFF_XT) + ((b * 8 + nT) * 8 + kT) * 16384;
#pragma unroll
        for (int it = 0; it < 4; ++it) {
            int item = it * 256 + tid;
            int n = item >> 3, k8 = item & 7;
            s16x8 h;
#pragma unroll
            for (int i = 0; i < 8; i++) h[i] = (short)fbf(lds[(k8 * 8 + i) * 129 + n]);
            *(s16x8*)(dst + SWZ(n * 128 + k8 * 16)) = h;
        }
    }
}

// MFMA projection GEMM: 64m x 64n tiles, BK=64, dbuf LDS. grid (10, 16, 4) = 640 blocks.
__global__ __launch_bounds__(256) void k_projm(
        const float* __restrict__ b1, const float* __restrict__ b2,
        const float* __restrict__ b3, float* __restrict__ ws) {
    __shared__ __align__(16) char smem[32768];   // 2 x (A 8KB + B 8KB)
    int tid = threadIdx.x, lane = tid & 63, wv = tid >> 6;
    int lidx = lane & 15, q = lane >> 4;
    int mT = blockIdx.x, nTT = blockIdx.y, b = blockIdx.z;
    const char* wtg = (const char*)(ws + OFF_WT) + (mT >> 1) * 8 * 16384 + (mT & 1) * 8192;
    const char* xtg = (const char*)(ws + OFF_XT) + (b * 8 + (nTT >> 1)) * 8 * 16384 + (nTT & 1) * 8192;

    f32x4 acc[4];
#pragma unroll
    for (int j = 0; j < 4; j++) acc[j] = (f32x4)0.f;

#define STAGE(kt, buf) do { \
        const char* ga_ = wtg + (kt) * 16384; \
        const char* gb_ = xtg + (kt) * 16384; \
        char* la_ = smem + (buf) * 16384; \
        char* lb_ = la_ + 8192; \
        _Pragma("unroll") \
        for (int c_ = 0; c_ < 2; c_++) { \
            GLD16(ga_ + c_ * 4096 + wv * 1024 + lane * 16, la_ + c_ * 4096 + wv * 1024); \
            GLD16(gb_ + c_ * 4096 + wv * 1024 + lane * 16, lb_ + c_ * 4096 + wv * 1024); \
        } \
    } while (0)

    STAGE(0, 0);
    __syncthreads();
    for (int kt = 0; kt < 8; kt++) {
        if (kt < 7) STAGE(kt + 1, (kt + 1) & 1);
        const char* la = smem + (kt & 1) * 16384;
        const char* lb = la + 8192;
#pragma unroll
        for (int ks = 0; ks < 2; ks++) {
            s16x8 af, bf[4];
            int kb = ks * 64 + q * 16;
            int arow = wv * 16 + lidx;
            af = *(const s16x8*)(la + SWZ(arow * 128 + kb));
#pragma unroll
            for (int f = 0; f < 4; f++) {
                int brow = f * 16 + lidx;
                bf[f] = *(const s16x8*)(lb + SWZ(brow * 128 + kb));
            }
#pragma unroll
            for (int nf = 0; nf < 4; nf++)
                acc[nf] = __builtin_amdgcn_mfma_f32_16x16x32_bf16(af, bf[nf], acc[nf], 0, 0, 0);
        }
        __syncthreads();
    }
#undef STAGE

    unsigned short* x1t = (unsigned short*)(ws + OFF_X1T);
    unsigned short* x2t = (unsigned short*)(ws + OFF_X2T);
    unsigned short* x3t = (unsigned short*)(ws + OFF_X3T);
    int mg = mT * 64 + wv * 16 + q * 4;
#pragma unroll
    for (int nf = 0; nf < 4; nf++) {
        int n = nTT * 64 + nf * 16 + lidx;
        float o[4];
        uint2 pk;
        if (mg < 64) {
#pragma unroll
            for (int r = 0; r < 4; r++)
                o[r] = ws[OFF_A0 + mg + r] * (acc[nf][r] + b1[mg + r]) + ws[OFF_C0 + mg + r];
            pk.x = pk2bf(o[0], o[1]); pk.y = pk2bf(o[2], o[3]);
            *(uint2*)(x1t + (size_t)(b * HWTOT + n) * 64 + mg) = pk;
        } else if (mg < 128) {
            int c = mg - 64;
#pragma unroll
            for (int r = 0; r < 4; r++)
                o[r] = ws[OFF_A0 + c + r] * (acc[nf][r] + b2[c + r]);
            pk.x = pk2bf(o[0], o[1]); pk.y = pk2bf(o[2], o[3]);
            *(uint2*)(x2t + (size_t)(b * HWTOT + n) * 64 + c) = pk;
        } else {
            int c = mg - 128;
#pragma unroll
            for (int r = 0; r < 4; r++)
                o[r] = acc[nf][r] + b3[c + r];
            pk.x = pk2bf(o[0], o[1]); pk.y = pk2bf(o[2], o[3]);
            *(uint2*)(x3t + (size_t)(b * HWTOT + n) * 512 + c) = pk;
        }
    }
}

// Fallback fp32 projection; bf16 outputs.
__global__ __launch_bounds__(256) void k_proj(
        const float* __restrict__ x,
        const float* __restrict__ w1, const float* __restrict__ b1,
        const float* __restrict__ w2, const float* __restrict__ b2,
        const float* __restrict__ w3, const float* __restrict__ b3,
        float* __restrict__ ws) {
    __shared__ __align__(16) float As[64 * 17];
    __shared__ __align__(16) float Bs[16 * 64];
    int tid = threadIdx.x;
    int n0 = blockIdx.x * 64;
    int mT = blockIdx.y;
    int b = blockIdx.z;
    int mq = tid >> 4, nq = tid & 15;
    float acc[4][4];
#pragma unroll
    for (int i = 0; i < 4; i++)
#pragma unroll
        for (int j = 0; j < 4; j++) acc[i][j] = 0.f;

    for (int k0 = 0; k0 < CIN; k0 += 16) {
#pragma unroll
        for (int i = 0; i < 4; i++) {
            int t = tid + i * 256;
            int k = t & 15, m = t >> 4;
            int mg = mT * 64 + m;
            const float* Wrow;
            if (mg < 64) Wrow = w1 + mg * CIN;
            else if (mg < 128) Wrow = w2 + (mg - 64) * CIN;
            else Wrow = w3 + (mg - 128) * CIN;
            As[m * 17 + k] = Wrow[k0 + k];
        }
#pragma unroll
        for (int i = 0; i < 4; i++) {
            int t = tid + i * 256;
            int n = t & 63, k = t >> 6;
            Bs[k * 64 + n] = x[(b * CIN + k0 + k) * HWTOT + n0 + n];
        }
        __syncthreads();
#pragma unroll
        for (int k = 0; k < 16; k++) {
            float4 bv = *(const float4*)&Bs[k * 64 + nq * 4];
            float av[4];
#pragma unroll
            for (int i = 0; i < 4; i++) av[i] = As[(mq * 4 + i) * 17 + k];
#pragma unroll
            for (int i = 0; i < 4; i++) {
                acc[i][0] += av[i] * bv.x;
                acc[i][1] += av[i] * bv.y;
                acc[i][2] += av[i] * bv.z;
                acc[i][3] += av[i] * bv.w;
            }
        }
        __syncthreads();
    }
    unsigned short* x1t = (unsigned short*)(ws + OFF_X1T);
    unsigned short* x2t = (unsigned short*)(ws + OFF_X2T);
    unsigned short* x3t = (unsigned short*)(ws + OFF_X3T);
#pragma unroll
    for (int i = 0; i < 4; i++) {
        int mg = mT * 64 + mq * 4 + i;
        if (mg < 64) {
            float bias = b1[mg];
            float aa = ws[OFF_A0 + mg], cc = ws[OFF_C0 + mg];
#pragma unroll
            for (int j = 0; j < 4; j++) {
                int n = n0 + nq * 4 + j;
                x1t[(size_t)(b * HWTOT + n) * 64 + mg] = fbf(aa * (acc[i][j] + bias) + cc);
            }
        } else if (mg < 128) {
            int r = mg - 64;
            float bias = b2[r];
            float aa = ws[OFF_A0 + r];
#pragma unroll
            for (int j = 0; j < 4; j++) {
                int n = n0 + nq * 4 + j;
                x2t[(size_t)(b * HWTOT + n) * 64 + r] = fbf(aa * (acc[i][j] + bias));
            }
        } else {
            float bias = b3[mg - 128];
#pragma unroll
            for (int j = 0; j < 4; j++) {
                int n = n0 + nq * 4 + j;
                x3t[(size_t)(b * HWTOT + n) * 512 + (mg - 128)] = fbf(acc[i][j] + bias);
            }
        }
    }
}

// Two INDEPENDENT pixels per 128-thread WG (one per wave, no barriers, no sharing).
// ph3 neighbor indices via wave-uniform ry/rx scalar tables (static indexing only).
__global__ __launch_bounds__(128, 4) void k_fused3(
        const float* __restrict__ ws, float* __restrict__ out) {
    __shared__ __align__(16) char smem[16384];  // 2 x 8KB t1/wgt slices

    int tid = threadIdx.x;
    int lane = tid & 63;
    int wv = tid >> 6;
    int lidx = lane & 15;
    int q = lane >> 4;

    int bid = blockIdx.x;
    int p = ((bid & 7) * 256 + (bid >> 3)) * 2 + wv;   // XCD-chunked swizzle
    int b = p >> 10;
    int n = p & 1023;
    int y = n >> 5, x0 = n & 31;

    char* t1p = smem + wv * 8192;

    const unsigned short* x1t = (const unsigned short*)(ws + OFF_X1T);
    const unsigned short* x2t = (const unsigned short*)(ws + OFF_X2T);
    const unsigned short* x3t = (const unsigned short*)(ws + OFF_X3T);
    const float* pm  = ws + OFF_PM;
    const unsigned short* w1b = (const unsigned short*)(ws + OFF_W1B);
    const unsigned short* w2f = (const unsigned short*)(ws + OFF_W2F);

    // wave-uniform neighbor tables (static indices only -> scalar regs)
    int ry[7], rx[7];
#pragma unroll
    for (int i = 0; i < 7; i++) {
        ry[i] = refl(y + i - 3) * 32;
        rx[i] = refl(x0 + i - 3);
    }

    // per-lane col data: nb, aux; issue x2 gathers immediately
    float pmn0 = pm[n * 2], pmn1 = pm[n * 2 + 1];
    float a064 = ws[OFF_A0 + 64], c064 = ws[OFF_C0 + 64];
    float a065 = ws[OFF_A0 + 65], c065 = ws[OFF_C0 + 65];
    float s64v[4], s65v[4];
    s16x8 xv[4][2];
#pragma unroll
    for (int ct = 0; ct < 4; ct++) {
        int col = lidx + 16 * ct;
        int di = col / 7 - 3, dj = col % 7 - 3;
        int nb = refl(y + di) * 32 + refl(x0 + dj);
        const unsigned short* x2r = x2t + (size_t)(b * HWTOT + nb) * 64 + q * 8;
        xv[ct][0] = *(const s16x8*)(x2r);
        xv[ct][1] = *(const s16x8*)(x2r + 32);
        float2 pmb = *(const float2*)(pm + nb * 2);
        s64v[ct] = fmaxf(fmaf(a064, pmn0 - pmb.x, c064), 0.f);
        s65v[ct] = fmaxf(fmaf(a065, pmn1 - pmb.y, c065), 0.f);
    }

    s16x8 af1[4][2];
#pragma unroll
    for (int cot = 0; cot < 4; cot++)
#pragma unroll
        for (int ks = 0; ks < 2; ks++)
            af1[cot][ks] = *(const s16x8*)(w1b + (lidx + 16 * cot) * 64 + ks * 32 + q * 8);

    s16x8 af2[4][2];
#pragma unroll
    for (int gt = 0; gt < 4; gt++)
#pragma unroll
        for (int ks2 = 0; ks2 < 2; ks2++)
            af2[gt][ks2] = *(const s16x8*)(w2f + ((gt * 2 + ks2) * 64 + lane) * 8);

    const unsigned short* x1r = x1t + (size_t)(b * HWTOT + n) * 64 + q * 8;
    float x1f[2][8];
    {
        s16x8 h0 = *(const s16x8*)(x1r);
        s16x8 h1 = *(const s16x8*)(x1r + 32);
#pragma unroll
        for (int i = 0; i < 8; i++) {
            x1f[0][i] = bf2f((unsigned short)h0[i]);
            x1f[1][i] = bf2f((unsigned short)h1[i]);
        }
    }

    // GEMM1: per col-tile, MFMA, epilogue -> t1 LDS
#pragma unroll
    for (int ct = 0; ct < 4; ct++) {
        int col = lidx + 16 * ct;
        f32x4 acc1[4];
#pragma unroll
        for (int cot = 0; cot < 4; cot++) acc1[cot] = (f32x4)0.f;
#pragma unroll
        for (int ks = 0; ks < 2; ks++) {
            s16x8 v = xv[ct][ks];
            union { s16x8 v; unsigned u[4]; } bb;
#pragma unroll
            for (int w = 0; w < 4; w++)
                bb.u[w] = pk2bf(
                    fmaxf(x1f[ks][2 * w]     - bf2f((unsigned short)v[2 * w]),     0.f),
                    fmaxf(x1f[ks][2 * w + 1] - bf2f((unsigned short)v[2 * w + 1]), 0.f));
#pragma unroll
            for (int cot = 0; cot < 4; cot++)
                acc1[cot] = __builtin_amdgcn_mfma_f32_16x16x32_bf16(af1[cot][ks], bb.v, acc1[cot], 0, 0, 0);
        }
#pragma unroll
        for (int cot = 0; cot < 4; cot++) {
            f32x4 wa = *(const f32x4*)(ws + OFF_W64 + cot * 16 + q * 4);
            f32x4 wb = *(const f32x4*)(ws + OFF_W65 + cot * 16 + q * 4);
            f32x4 cc = *(const f32x4*)(ws + OFF_C1V + cot * 16 + q * 4);
            float t[4];
#pragma unroll
            for (int r = 0; r < 4; r++)
                t[r] = fmaxf(acc1[cot][r] + wa[r] * s64v[ct] + wb[r] * s65v[ct] + cc[r], 0.f);
            uint2 pk;
            pk.x = pk2bf(t[0], t[1]);
            pk.y = pk2bf(t[2], t[3]);
            int byte = col * 128 + cot * 32 + q * 8;
            *(uint2*)(t1p + SWZ(byte)) = pk;
        }
    }

    // GEMM2 (swapped: D[k][g]) + softmax over k (in-wave LDS ordering suffices)
    unsigned held[4][4][2];
#pragma unroll
    for (int gt = 0; gt < 4; gt++) {
        f32x4 acc2[4];
#pragma unroll
        for (int kt = 0; kt < 4; kt++) acc2[kt] = (f32x4)0.f;
#pragma unroll
        for (int kt = 0; kt < 4; kt++) {
#pragma unroll
            for (int ks2 = 0; ks2 < 2; ks2++) {
                int byte = (lidx + 16 * kt) * 128 + ks2 * 64 + q * 16;
                s16x8 a = *(const s16x8*)(t1p + SWZ(byte));
                acc2[kt] = __builtin_amdgcn_mfma_f32_16x16x32_bf16(a, af2[gt][ks2], acc2[kt], 0, 0, 0);
            }
        }
        float mx = -1e30f;
#pragma unroll
        for (int kt = 0; kt < 3; kt++)
#pragma unroll
            for (int r = 0; r < 4; r++) mx = fmaxf(mx, acc2[kt][r]);
        if (q == 0) mx = fmaxf(mx, acc2[3][0]);
        mx = fmaxf(mx, __shfl_xor(mx, 16));
        mx = fmaxf(mx, __shfl_xor(mx, 32));
        float e[4][4];
        float sum = 0.f;
#pragma unroll
        for (int kt = 0; kt < 4; kt++)
#pragma unroll
            for (int r = 0; r < 4; r++) {
                bool valid = (kt < 3) || (q == 0 && r == 0);
                float ev = valid ? exp2f((acc2[kt][r] - mx) * 1.44269504f) : 0.f;
                e[kt][r] = ev;
                sum += ev;
            }
        sum += __shfl_xor(sum, 16);
        sum += __shfl_xor(sum, 32);
        float inv = 1.f / sum;
#pragma unroll
        for (int kt = 0; kt < 4; kt++) {
            held[gt][kt][0] = pk2bf(e[kt][0] * inv, e[kt][1] * inv);
            held[gt][kt][1] = pk2bf(e[kt][2] * inv, e[kt][3] * inv);
        }
    }

    // overwrite t1 buffer with wgt [g][k] bf16
#pragma unroll
    for (int gt = 0; gt < 4; gt++)
#pragma unroll
        for (int kt = 0; kt < 4; kt++) {
            int byte = (lidx + 16 * gt) * 128 + kt * 32 + q * 8;
            uint2 pk;
            pk.x = held[gt][kt][0];
            pk.y = held[gt][kt][1];
            *(uint2*)(t1p + SWZ(byte)) = pk;
        }

    // aggregation: lane owns 8 channels (g = lane); nb via static ry/rx tables
    s16x8 wrow[7];
#pragma unroll
    for (int i = 0; i < 7; i++)
        wrow[i] = *(const s16x8*)(t1p + SWZ(lane * 128 + i * 16));

    f32x4 a30 = (f32x4)0.f, a31 = (f32x4)0.f;
    const unsigned short* x3b = x3t + (size_t)b * HWTOT * 512 + lane * 8;
#pragma unroll
    for (int k = 0; k < KKW; k++) {
        int nb = ry[k / 7] + rx[k % 7];
        float w = bf2f((unsigned short)wrow[k >> 3][k & 7]);
        s16x8 v = *(const s16x8*)(x3b + (size_t)nb * 512);
#pragma unroll
        for (int r = 0; r < 4; r++) {
            a30[r] = fmaf(w, bf2f((unsigned short)v[r]), a30[r]);
            a31[r] = fmaf(w, bf2f((unsigned short)v[4 + r]), a31[r]);
        }
    }
    float* ob = out + ((size_t)b * COUT + lane * 8) * HWTOT + n;
#pragma unroll
    for (int i = 0; i < 4; i++) ob[i * HWTOT] = a30[i];
#pragma unroll
    for (int i = 0; i < 4; i++) ob[(i + 4) * HWTOT] = a31[i];
}

// Monolithic 1-wave fallback for small ws.
__global__ __launch_bounds__(64, 4) void k_fused(
        const float* __restrict__ ws, float* __restrict__ out) {
    __shared__ __align__(16) char smem[8448];

    int lane = threadIdx.x;
    int lidx = lane & 15;
    int q = lane >> 4;

    int bid = blockIdx.x;
    int p = (bid & 7) * 512 + (bid >> 3);
    int b = p >> 10;
    int n = p & 1023;
    int y = n >> 5, x0 = n & 31;

    char* t1p = smem;
    int* nbo = (int*)(smem + 8192);

    const unsigned short* x1t = (const unsigned short*)(ws + OFF_X1T);
    const unsigned short* x2t = (const unsigned short*)(ws + OFF_X2T);
    const unsigned short* x3t = (const unsigned short*)(ws + OFF_X3T);
    const float* pm  = ws + OFF_PM;
    const unsigned short* w1b = (const unsigned short*)(ws + OFF_W1B);
    const unsigned short* w2f = (const unsigned short*)(ws + OFF_W2F);

    {
        int di = lane / 7 - 3, dj = lane % 7 - 3;
        nbo[lane] = refl(y + di) * 32 + refl(x0 + dj);
    }

    float pmn0 = pm[n * 2], pmn1 = pm[n * 2 + 1];
    float a064 = ws[OFF_A0 + 64], c064 = ws[OFF_C0 + 64];
    float a065 = ws[OFF_A0 + 65], c065 = ws[OFF_C0 + 65];
    float s64v[4], s65v[4];
    s16x8 xv[4][2];
#pragma unroll
    for (int ct = 0; ct < 4; ct++) {
        int col = lidx + 16 * ct;
        int di = col / 7 - 3, dj = col % 7 - 3;
        int nb = refl(y + di) * 32 + refl(x0 + dj);
        const unsigned short* x2r = x2t + (size_t)(b * HWTOT + nb) * 64 + q * 8;
        xv[ct][0] = *(const s16x8*)(x2r);
        xv[ct][1] = *(const s16x8*)(x2r + 32);
        float2 pmb = *(const float2*)(pm + nb * 2);
        s64v[ct] = fmaxf(fmaf(a064, pmn0 - pmb.x, c064), 0.f);
        s65v[ct] = fmaxf(fmaf(a065, pmn1 - pmb.y, c065), 0.f);
    }

    s16x8 af1[4][2];
#pragma unroll
    for (int cot = 0; cot < 4; cot++)
#pragma unroll
        for (int ks = 0; ks < 2; ks++)
            af1[cot][ks] = *(const s16x8*)(w1b + (lidx + 16 * cot) * 64 + ks * 32 + q * 8);

    s16x8 af2[4][2];
#pragma unroll
    for (int gt = 0; gt < 4; gt++)
#pragma unroll
        for (int ks2 = 0; ks2 < 2; ks2++)
            af2[gt][ks2] = *(const s16x8*)(w2f + ((gt * 2 + ks2) * 64 + lane) * 8);

    const unsigned short* x1r = x1t + (size_t)(b * HWTOT + n) * 64 + q * 8;
    float x1f[2][8];
    {
        s16x8 h0 = *(const s16x8*)(x1r);
        s16x8 h1 = *(const s16x8*)(x1r + 32);
#pragma unroll
        for (int i = 0; i < 8; i++) {
            x1f[0][i] = bf2f((unsigned short)h0[i]);
            x1f[1][i] = bf2f((unsigned short)h1[i]);
        }
    }

#pragma unroll
    for (int ct = 0; ct < 4; ct++) {
        int col = lidx + 16 * ct;
        f32x4 acc1[4];
#pragma unroll
        for (int cot = 0; cot < 4; cot++) acc1[cot] = (f32x4)0.f;
#pragma unroll
        for (int ks = 0; ks < 2; ks++) {
            s16x8 v = xv[ct][ks];
            union { s16x8 v; unsigned u[4]; } bb;
#pragma unroll
            for (int w = 0; w < 4; w++)
                bb.u[w] = pk2bf(
                    fmaxf(x1f[ks][2 * w]     - bf2f((unsigned short)v[2 * w]),     0.f),
                    fmaxf(x1f[ks][2 * w + 1] - bf2f((unsigned short)v[2 * w + 1]), 0.f));
#pragma unroll
            for (int cot = 0; cot < 4; cot++)
                acc1[cot] = __builtin_amdgcn_mfma_f32_16x16x32_bf16(af1[cot][ks], bb.v, acc1[cot], 0, 0, 0);
        }
#pragma unroll
        for (int cot = 0; cot < 4; cot++) {
            f32x4 wa = *(const f32x4*)(ws + OFF_W64 + cot * 16 + q * 4);
            f32x4 wb = *(const f32x4*)(ws + OFF_W65 + cot * 16 + q * 4);
            f32x4 cc = *(const f32x4*)(ws + OFF_C1V + cot * 16 + q * 4);
            float t[4];
#pragma unroll
            for (int r = 0; r < 4; r++)
                t[r] = fmaxf(acc1[cot][r] + wa[r] * s64v[ct] + wb[r] * s65v[ct] + cc[r], 0.f);
            uint2 pk;
            pk.x = pk2bf(t[0], t[1]);
            pk.y = pk2bf(t[2], t[3]);
            int byte = col * 128 + cot * 32 + q * 8;
            *(uint2*)(t1p + SWZ(byte)) = pk;
        }
    }

    unsigned held[4][4][2];
#pragma unroll
    for (int gt = 0; gt < 4; gt++) {
        f32x4 acc2[4];
#pragma unroll
        for (int kt = 0; kt < 4; kt++) acc2[kt] = (f32x4)0.f;
#pragma unroll
        for (int kt = 0; kt < 4; kt++) {
#pragma unroll
            for (int ks2 = 0; ks2 < 2; ks2++) {
                int byte = (lidx + 16 * kt) * 128 + ks2 * 64 + q * 16;
                s16x8 a = *(const s16x8*)(t1p + SWZ(byte));
                acc2[kt] = __builtin_amdgcn_mfma_f32_16x16x32_bf16(a, af2[gt][ks2], acc2[kt], 0, 0, 0);
            }
        }
        float mx = -1e30f;
#pragma unroll
        for (int kt = 0; kt < 3; kt++)
#pragma unroll
            for (int r = 0; r < 4; r++) mx = fmaxf(mx, acc2[kt][r]);
        if (q == 0) mx = fmaxf(mx, acc2[3][0]);
        mx = fmaxf(mx, __shfl_xor(mx, 16));
        mx = fmaxf(mx, __shfl_xor(mx, 32));
        float e[4][4];
        float sum = 0.f;
#pragma unroll
        for (int kt = 0; kt < 4; kt++)
#pragma unroll
            for (int r = 0; r < 4; r++) {
                bool valid = (kt < 3) || (q == 0 && r == 0);
                float ev = valid ? exp2f((acc2[kt][r] - mx) * 1.44269504f) : 0.f;
                e[kt][r] = ev;
                sum += ev;
            }
        sum += __shfl_xor(sum, 16);
        sum += __shfl_xor(sum, 32);
        float inv = 1.f / sum;
#pragma unroll
        for (int kt = 0; kt < 4; kt++) {
            held[gt][kt][0] = pk2bf(e[kt][0] * inv, e[kt][1] * inv);
            held[gt][kt][1] = pk2bf(e[kt][2] * inv, e[kt][3] * inv);
        }
    }

#pragma unroll
    for (int gt = 0; gt < 4; gt++)
#pragma unroll
        for (int kt = 0; kt < 4; kt++) {
            int byte = (lidx + 16 * gt) * 128 + kt * 32 + q * 8;
            uint2 pk;
            pk.x = held[gt][kt][0];
            pk.y = held[gt][kt][1];
            *(uint2*)(t1p + SWZ(byte)) = pk;
        }

    s16x8 wrow[7];
#pragma unroll
    for (int i = 0; i < 7; i++)
        wrow[i] = *(const s16x8*)(t1p + SWZ(lane * 128 + i * 16));

    f32x4 a30 = (f32x4)0.f, a31 = (f32x4)0.f;
    const unsigned short* x3b = x3t + (size_t)b * HWTOT * 512 + lane * 8;
#pragma unroll
    for (int k = 0; k < KKW; k++) {
        int nb = nbo[k];
        float w = bf2f((unsigned short)wrow[k >> 3][k & 7]);
        s16x8 v = *(const s16x8*)(x3b + (size_t)nb * 512);
#pragma unroll
        for (int r = 0; r < 4; r++) {
            a30[r] = fmaf(w, bf2f((unsigned short)v[r]), a30[r]);
            a31[r] = fmaf(w, bf2f((unsigned short)v[4 + r]), a31[r]);
        }
    }
    float* ob = out + ((size_t)b * COUT + lane * 8) * HWTOT + n;
#pragma unroll
    for (int i = 0; i < 4; i++) ob[i * HWTOT] = a30[i];
#pragma unroll
    for (int i = 0; i < 4; i++) ob[(i + 4) * HWTOT] = a31[i];
}

extern "C" void kernel_launch(void* const* d_in, const int* in_sizes, int n_in,
                              void* d_out, int out_size, void* d_ws, size_t ws_size,
                              hipStream_t stream) {
    const float* x = (const float*)d_in[0];
    const float* w1 = (const float*)d_in[1];
    const float* b1 = (const float*)d_in[2];
    const float* w2 = (const float*)d_in[3];
    const float* b2 = (const float*)d_in[4];
    const float* w3 = (const float*)d_in[5];
    const float* b3 = (const float*)d_in[6];
    const float* wp = (const float*)d_in[7];
    const float* bp = (const float*)d_in[8];
    const float* g0 = (const float*)d_in[9];
    const float* be0 = (const float*)d_in[10];
    const float* m0 = (const float*)d_in[11];
    const float* v0 = (const float*)d_in[12];
    const float* wcw1 = (const float*)d_in[13];
    const float* g1 = (const float*)d_in[14];
    const float* be1 = (const float*)d_in[15];
    const float* m1 = (const float*)d_in[16];
    const float* v1 = (const float*)d_in[17];
    const float* wcw2 = (const float*)d_in[18];
    float* ws = (float*)d_ws;
    float* out = (float*)d_out;

    if (ws_size >= WS_NEED_FLOATS * 4ull) {
        k_prep<<<297, 256, 0, stream>>>(x, w1, w2, w3, wp, bp, g0, be0, m0, v0,
                                        wcw1, g1, be1, m1, v1, wcw2, ws);
        k_projm<<<dim3(10, 16, 4), 256, 0, stream>>>(b1, b2, b3, ws);
        k_fused3<<<2048, 128, 0, stream>>>(ws, out);
    } else {
        k_setup<<<1, 256, 0, stream>>>(wp, bp, g0, be0, m0, v0, wcw1, g1, be1, m1, v1, wcw2, ws);
        k_proj<<<dim3(16, 10, 4), 256, 0, stream>>>(x, w1, b1, w2, b2, w3, b3, ws);
        k_fused<<<4096, 64, 0, stream>>>(ws, out);
    }
}

// Round 17
// 56.812 us; speedup vs baseline: 1.0079x; 1.0079x over previous
//
#include <hip/hip_runtime.h>
#include <hip/hip_bf16.h>
#include <math.h>

typedef float f32x4 __attribute__((ext_vector_type(4)));
typedef short s16x8 __attribute__((ext_vector_type(8)));

#define KKW 49
#define HWTOT 1024
#define CIN 512
#define COUT 512

// ws float offsets (x1t/x2t/x3t regions hold bf16)
#define OFF_X1T 0
#define OFF_X2T 262144
#define OFF_X3T 524288
#define OFF_PM  2621440
#define OFF_A0  2623488
#define OFF_C0  2623554
#define OFF_W64 2623620
#define OFF_W65 2623684
#define OFF_C1V 2623748
#define OFF_W1B 2623812   /* 4096 bf16 (a1-folded wcw1[:, :64]) */
#define OFF_W2B 2625860   /* reserved */
#define OFF_W2F 2627908   /* 4096 bf16 (wcw2^T pre-fragmented for GEMM2 B) */
#define OFF_WT  2629956   /* 640x512 bf16, 5x8 tiles of [128m][64k] swizzled */
#define OFF_XT  2793796   /* 4x1024x512 bf16, 4x8x8 tiles of [128n][64k] swizzled */
#define WS_NEED_FLOATS 3842372ull

#define SWZ(bb)  ((bb) ^ ((((bb) >> 7) & 7) << 4))

#define GLD16(g, l) __builtin_amdgcn_global_load_lds( \
    (const __attribute__((address_space(1))) void*)(g), \
    (__attribute__((address_space(3))) void*)(l), 16, 0, 0)

__device__ __forceinline__ int refl(int m) {
    if (m < 0) m = -m;
    if (m > 31) m = 62 - m;
    return m;
}

__device__ __forceinline__ unsigned short fbf(float f) {
    unsigned u = __builtin_bit_cast(unsigned, f);
    unsigned r = u + 0x7fffu + ((u >> 16) & 1u);
    return (unsigned short)(r >> 16);
}

__device__ __forceinline__ unsigned pk2bf(float a, float b) {
    float2 f2; f2.x = a; f2.y = b;
    __hip_bfloat162 h = __float22bfloat162_rn(f2);
    union { __hip_bfloat162 h2; unsigned u; } cv;
    cv.h2 = h;
    return cv.u;
}

__device__ __forceinline__ float bf2f(unsigned short u) {
    unsigned v = (unsigned)u << 16;
    return __builtin_bit_cast(float, v);
}

__device__ __forceinline__ void setup_body(
        int tid,
        const float* __restrict__ wp, const float* __restrict__ bp,
        const float* __restrict__ g0, const float* __restrict__ be0,
        const float* __restrict__ m0, const float* __restrict__ v0,
        const float* __restrict__ wcw1,
        const float* __restrict__ g1, const float* __restrict__ be1,
        const float* __restrict__ m1, const float* __restrict__ v1,
        const float* __restrict__ wcw2,
        float* __restrict__ ws) {
    float* pm = ws + OFF_PM;
    for (int n = tid; n < HWTOT; n += 256) {
        int xx = n & 31, yy = n >> 5;
        float lw = -1.f + (2.f / 31.f) * xx;
        float lh = -1.f + (2.f / 31.f) * yy;
        pm[n * 2 + 0] = wp[0] * lw + wp[1] * lh + bp[0];
        pm[n * 2 + 1] = wp[2] * lw + wp[3] * lh + bp[1];
    }
    if (tid < 66) {
        float a = g0[tid] * rsqrtf(v0[tid] + 1e-5f);
        ws[OFF_A0 + tid] = a;
        ws[OFF_C0 + tid] = be0[tid] - m0[tid] * a;
    }
    if (tid < 64) {
        float a1c = g1[tid] * rsqrtf(v1[tid] + 1e-5f);
        ws[OFF_W64 + tid] = a1c * wcw1[tid * 66 + 64];
        ws[OFF_W65 + tid] = a1c * wcw1[tid * 66 + 65];
        ws[OFF_C1V + tid] = be1[tid] - m1[tid] * a1c;
    }
    unsigned short* w1b = (unsigned short*)(ws + OFF_W1B);
    unsigned short* w2f = (unsigned short*)(ws + OFF_W2F);
    for (int t = tid; t < 4096; t += 256) {
        int co = t >> 6, r = t & 63;
        float a1c = g1[co] * rsqrtf(v1[co] + 1e-5f);
        w1b[t] = fbf(a1c * wcw1[co * 66 + r]);
        int j = t & 7, idx = t >> 3;
        int ft = idx >> 6, l = idx & 63;
        int gt = ft >> 1, ks2 = ft & 1;
        int g = (l & 15) + gt * 16;
        int c2 = ks2 * 32 + (l >> 4) * 8 + j;
        w2f[t] = fbf(wcw2[g * 64 + c2]);
    }
}

__global__ void k_setup(const float* __restrict__ wp, const float* __restrict__ bp,
                        const float* __restrict__ g0, const float* __restrict__ be0,
                        const float* __restrict__ m0, const float* __restrict__ v0,
                        const float* __restrict__ wcw1,
                        const float* __restrict__ g1, const float* __restrict__ be1,
                        const float* __restrict__ m1, const float* __restrict__ v1,
                        const float* __restrict__ wcw2,
                        float* __restrict__ ws) {
    setup_body(threadIdx.x, wp, bp, g0, be0, m0, v0, wcw1, g1, be1, m1, v1, wcw2, ws);
}

// Pack weights (blocks 0..39), x-transpose (blocks 40..295), setup (block 296).
__global__ __launch_bounds__(256) void k_prep(
        const float* __restrict__ x,
        const float* __restrict__ w1, const float* __restrict__ w2,
        const float* __restrict__ w3,
        const float* __restrict__ wp, const float* __restrict__ bp,
        const float* __restrict__ g0, const float* __restrict__ be0,
        const float* __restrict__ m0, const float* __restrict__ v0,
        const float* __restrict__ wcw1,
        const float* __restrict__ g1, const float* __restrict__ be1,
        const float* __restrict__ m1, const float* __restrict__ v1,
        const float* __restrict__ wcw2,
        float* __restrict__ ws) {
    int bid = blockIdx.x;
    int tid = threadIdx.x;
    if (bid == 296) {
        setup_body(tid, wp, bp, g0, be0, m0, v0, wcw1, g1, be1, m1, v1, wcw2, ws);
    } else if (bid < 40) {
        int mT = bid / 8, kT = bid % 8;
        char* dst = (char*)(ws + OFF_WT) + (mT * 8 + kT) * 16384;
#pragma unroll
        for (int it = 0; it < 4; ++it) {
            int item = it * 256 + tid;
            int m = item >> 3, k8 = item & 7;
            int mg = mT * 128 + m;
            const float* src;
            if (mg < 64) src = w1 + mg * CIN;
            else if (mg < 128) src = w2 + (mg - 64) * CIN;
            else src = w3 + (mg - 128) * CIN;
            int k0 = kT * 64 + k8 * 8;
            s16x8 h;
#pragma unroll
            for (int i = 0; i < 8; i++) h[i] = (short)fbf(src[k0 + i]);
            *(s16x8*)(dst + SWZ(m * 128 + k8 * 16)) = h;
        }
    } else {
        __shared__ float lds[64 * 129];
        int t = bid - 40;  // b(4) nT(8) kT(8)
        int b = t >> 6, nT = (t >> 3) & 7, kT = t & 7;
        const float* src = x + (b * CIN + kT * 64) * HWTOT + nT * 128;
#pragma unroll
        for (int it = 0; it < 8; ++it) {
            int item = it * 256 + tid;
            int kk = item >> 5, n4 = item & 31;
            float4 v = *(const float4*)(src + kk * HWTOT + n4 * 4);
            float* d = &lds[kk * 129 + n4 * 4];
            d[0] = v.x; d[1] = v.y; d[2] = v.z; d[3] = v.w;
        }
        __syncthreads();
        char* dst = (char*)(ws + OFF_XT) + ((b * 8 + nT) * 8 + kT) * 16384;
#pragma unroll
        for (int it = 0; it < 4; ++it) {
            int item = it * 256 + tid;
            int n = item >> 3, k8 = item & 7;
            s16x8 h;
#pragma unroll
            for (int i = 0; i < 8; i++) h[i] = (short)fbf(lds[(k8 * 8 + i) * 129 + n]);
            *(s16x8*)(dst + SWZ(n * 128 + k8 * 16)) = h;
        }
    }
}

// MFMA projection GEMM: 64m x 64n tiles, BK=64, dbuf LDS. grid (10, 16, 4) = 640 blocks.
__global__ __launch_bounds__(256) void k_projm(
        const float* __restrict__ b1, const float* __restrict__ b2,
        const float* __restrict__ b3, float* __restrict__ ws) {
    __shared__ __align__(16) char smem[32768];   // 2 x (A 8KB + B 8KB)
    int tid = threadIdx.x, lane = tid & 63, wv = tid >> 6;
    int lidx = lane & 15, q = lane >> 4;
    int mT = blockIdx.x, nTT = blockIdx.y, b = blockIdx.z;
    const char* wtg = (const char*)(ws + OFF_WT) + (mT >> 1) * 8 * 16384 + (mT & 1) * 8192;
    const char* xtg = (const char*)(ws + OFF_XT) + (b * 8 + (nTT >> 1)) * 8 * 16384 + (nTT & 1) * 8192;

    f32x4 acc[4];
#pragma unroll
    for (int j = 0; j < 4; j++) acc[j] = (f32x4)0.f;

#define STAGE(kt, buf) do { \
        const char* ga_ = wtg + (kt) * 16384; \
        const char* gb_ = xtg + (kt) * 16384; \
        char* la_ = smem + (buf) * 16384; \
        char* lb_ = la_ + 8192; \
        _Pragma("unroll") \
        for (int c_ = 0; c_ < 2; c_++) { \
            GLD16(ga_ + c_ * 4096 + wv * 1024 + lane * 16, la_ + c_ * 4096 + wv * 1024); \
            GLD16(gb_ + c_ * 4096 + wv * 1024 + lane * 16, lb_ + c_ * 4096 + wv * 1024); \
        } \
    } while (0)

    STAGE(0, 0);
    __syncthreads();
    for (int kt = 0; kt < 8; kt++) {
        if (kt < 7) STAGE(kt + 1, (kt + 1) & 1);
        const char* la = smem + (kt & 1) * 16384;
        const char* lb = la + 8192;
#pragma unroll
        for (int ks = 0; ks < 2; ks++) {
            s16x8 af, bf[4];
            int kb = ks * 64 + q * 16;
            int arow = wv * 16 + lidx;
            af = *(const s16x8*)(la + SWZ(arow * 128 + kb));
#pragma unroll
            for (int f = 0; f < 4; f++) {
                int brow = f * 16 + lidx;
                bf[f] = *(const s16x8*)(lb + SWZ(brow * 128 + kb));
            }
#pragma unroll
            for (int nf = 0; nf < 4; nf++)
                acc[nf] = __builtin_amdgcn_mfma_f32_16x16x32_bf16(af, bf[nf], acc[nf], 0, 0, 0);
        }
        __syncthreads();
    }
#undef STAGE

    unsigned short* x1t = (unsigned short*)(ws + OFF_X1T);
    unsigned short* x2t = (unsigned short*)(ws + OFF_X2T);
    unsigned short* x3t = (unsigned short*)(ws + OFF_X3T);
    int mg = mT * 64 + wv * 16 + q * 4;
#pragma unroll
    for (int nf = 0; nf < 4; nf++) {
        int n = nTT * 64 + nf * 16 + lidx;
        float o[4];
        uint2 pk;
        if (mg < 64) {
#pragma unroll
            for (int r = 0; r < 4; r++)
                o[r] = ws[OFF_A0 + mg + r] * (acc[nf][r] + b1[mg + r]) + ws[OFF_C0 + mg + r];
            pk.x = pk2bf(o[0], o[1]); pk.y = pk2bf(o[2], o[3]);
            *(uint2*)(x1t + (size_t)(b * HWTOT + n) * 64 + mg) = pk;
        } else if (mg < 128) {
            int c = mg - 64;
#pragma unroll
            for (int r = 0; r < 4; r++)
                o[r] = ws[OFF_A0 + c + r] * (acc[nf][r] + b2[c + r]);
            pk.x = pk2bf(o[0], o[1]); pk.y = pk2bf(o[2], o[3]);
            *(uint2*)(x2t + (size_t)(b * HWTOT + n) * 64 + c) = pk;
        } else {
            int c = mg - 128;
#pragma unroll
            for (int r = 0; r < 4; r++)
                o[r] = acc[nf][r] + b3[c + r];
            pk.x = pk2bf(o[0], o[1]); pk.y = pk2bf(o[2], o[3]);
            *(uint2*)(x3t + (size_t)(b * HWTOT + n) * 512 + c) = pk;
        }
    }
}

// Fallback fp32 projection; bf16 outputs.
__global__ __launch_bounds__(256) void k_proj(
        const float* __restrict__ x,
        const float* __restrict__ w1, const float* __restrict__ b1,
        const float* __restrict__ w2, const float* __restrict__ b2,
        const float* __restrict__ w3, const float* __restrict__ b3,
        float* __restrict__ ws) {
    __shared__ __align__(16) float As[64 * 17];
    __shared__ __align__(16) float Bs[16 * 64];
    int tid = threadIdx.x;
    int n0 = blockIdx.x * 64;
    int mT = blockIdx.y;
    int b = blockIdx.z;
    int mq = tid >> 4, nq = tid & 15;
    float acc[4][4];
#pragma unroll
    for (int i = 0; i < 4; i++)
#pragma unroll
        for (int j = 0; j < 4; j++) acc[i][j] = 0.f;

    for (int k0 = 0; k0 < CIN; k0 += 16) {
#pragma unroll
        for (int i = 0; i < 4; i++) {
            int t = tid + i * 256;
            int k = t & 15, m = t >> 4;
            int mg = mT * 64 + m;
            const float* Wrow;
            if (mg < 64) Wrow = w1 + mg * CIN;
            else if (mg < 128) Wrow = w2 + (mg - 64) * CIN;
            else Wrow = w3 + (mg - 128) * CIN;
            As[m * 17 + k] = Wrow[k0 + k];
        }
#pragma unroll
        for (int i = 0; i < 4; i++) {
            int t = tid + i * 256;
            int n = t & 63, k = t >> 6;
            Bs[k * 64 + n] = x[(b * CIN + k0 + k) * HWTOT + n0 + n];
        }
        __syncthreads();
#pragma unroll
        for (int k = 0; k < 16; k++) {
            float4 bv = *(const float4*)&Bs[k * 64 + nq * 4];
            float av[4];
#pragma unroll
            for (int i = 0; i < 4; i++) av[i] = As[(mq * 4 + i) * 17 + k];
#pragma unroll
            for (int i = 0; i < 4; i++) {
                acc[i][0] += av[i] * bv.x;
                acc[i][1] += av[i] * bv.y;
                acc[i][2] += av[i] * bv.z;
                acc[i][3] += av[i] * bv.w;
            }
        }
        __syncthreads();
    }
    unsigned short* x1t = (unsigned short*)(ws + OFF_X1T);
    unsigned short* x2t = (unsigned short*)(ws + OFF_X2T);
    unsigned short* x3t = (unsigned short*)(ws + OFF_X3T);
#pragma unroll
    for (int i = 0; i < 4; i++) {
        int mg = mT * 64 + mq * 4 + i;
        if (mg < 64) {
            float bias = b1[mg];
            float aa = ws[OFF_A0 + mg], cc = ws[OFF_C0 + mg];
#pragma unroll
            for (int j = 0; j < 4; j++) {
                int n = n0 + nq * 4 + j;
                x1t[(size_t)(b * HWTOT + n) * 64 + mg] = fbf(aa * (acc[i][j] + bias) + cc);
            }
        } else if (mg < 128) {
            int r = mg - 64;
            float bias = b2[r];
            float aa = ws[OFF_A0 + r];
#pragma unroll
            for (int j = 0; j < 4; j++) {
                int n = n0 + nq * 4 + j;
                x2t[(size_t)(b * HWTOT + n) * 64 + r] = fbf(aa * (acc[i][j] + bias));
            }
        } else {
            float bias = b3[mg - 128];
#pragma unroll
            for (int j = 0; j < 4; j++) {
                int n = n0 + nq * 4 + j;
                x3t[(size_t)(b * HWTOT + n) * 512 + (mg - 128)] = fbf(acc[i][j] + bias);
            }
        }
    }
}

// One wave = one pixel = one workgroup. ph3 ROLLED (unroll 7) to shrink code size:
// per-k weight read from LDS (u16), neighbor index from nbo LDS array.
__global__ __launch_bounds__(64, 4) void k_fused(
        const float* __restrict__ ws, float* __restrict__ out) {
    __shared__ __align__(16) char smem[8448];  // t1/wgt 8KB + nbo 256B

    int lane = threadIdx.x;
    int lidx = lane & 15;
    int q = lane >> 4;

    int bid = blockIdx.x;
    int p = (bid & 7) * 512 + (bid >> 3);   // XCD-chunked swizzle
    int b = p >> 10;
    int n = p & 1023;
    int y = n >> 5, x0 = n & 31;

    char* t1p = smem;
    int* nbo = (int*)(smem + 8192);

    const unsigned short* x1t = (const unsigned short*)(ws + OFF_X1T);
    const unsigned short* x2t = (const unsigned short*)(ws + OFF_X2T);
    const unsigned short* x3t = (const unsigned short*)(ws + OFF_X3T);
    const float* pm  = ws + OFF_PM;
    const unsigned short* w1b = (const unsigned short*)(ws + OFF_W1B);
    const unsigned short* w2f = (const unsigned short*)(ws + OFF_W2F);

    // nbo for ph3 (LDS)
    {
        int di = lane / 7 - 3, dj = lane % 7 - 3;
        nbo[lane] = refl(y + di) * 32 + refl(x0 + dj);
    }

    // per-lane col data: nb, aux; issue x2 gathers immediately
    float pmn0 = pm[n * 2], pmn1 = pm[n * 2 + 1];
    float a064 = ws[OFF_A0 + 64], c064 = ws[OFF_C0 + 64];
    float a065 = ws[OFF_A0 + 65], c065 = ws[OFF_C0 + 65];
    float s64v[4], s65v[4];
    s16x8 xv[4][2];
#pragma unroll
    for (int ct = 0; ct < 4; ct++) {
        int col = lidx + 16 * ct;
        int di = col / 7 - 3, dj = col % 7 - 3;
        int nb = refl(y + di) * 32 + refl(x0 + dj);
        const unsigned short* x2r = x2t + (size_t)(b * HWTOT + nb) * 64 + q * 8;
        xv[ct][0] = *(const s16x8*)(x2r);
        xv[ct][1] = *(const s16x8*)(x2r + 32);
        float2 pmb = *(const float2*)(pm + nb * 2);
        s64v[ct] = fmaxf(fmaf(a064, pmn0 - pmb.x, c064), 0.f);
        s65v[ct] = fmaxf(fmaf(a065, pmn1 - pmb.y, c065), 0.f);
    }

    s16x8 af1[4][2];
#pragma unroll
    for (int cot = 0; cot < 4; cot++)
#pragma unroll
        for (int ks = 0; ks < 2; ks++)
            af1[cot][ks] = *(const s16x8*)(w1b + (lidx + 16 * cot) * 64 + ks * 32 + q * 8);

    s16x8 af2[4][2];
#pragma unroll
    for (int gt = 0; gt < 4; gt++)
#pragma unroll
        for (int ks2 = 0; ks2 < 2; ks2++)
            af2[gt][ks2] = *(const s16x8*)(w2f + ((gt * 2 + ks2) * 64 + lane) * 8);

    const unsigned short* x1r = x1t + (size_t)(b * HWTOT + n) * 64 + q * 8;
    float x1f[2][8];
    {
        s16x8 h0 = *(const s16x8*)(x1r);
        s16x8 h1 = *(const s16x8*)(x1r + 32);
#pragma unroll
        for (int i = 0; i < 8; i++) {
            x1f[0][i] = bf2f((unsigned short)h0[i]);
            x1f[1][i] = bf2f((unsigned short)h1[i]);
        }
    }

    // GEMM1: per col-tile, MFMA, epilogue -> t1 LDS
#pragma unroll
    for (int ct = 0; ct < 4; ct++) {
        int col = lidx + 16 * ct;
        f32x4 acc1[4];
#pragma unroll
        for (int cot = 0; cot < 4; cot++) acc1[cot] = (f32x4)0.f;
#pragma unroll
        for (int ks = 0; ks < 2; ks++) {
            s16x8 v = xv[ct][ks];
            union { s16x8 v; unsigned u[4]; } bb;
#pragma unroll
            for (int w = 0; w < 4; w++)
                bb.u[w] = pk2bf(
                    fmaxf(x1f[ks][2 * w]     - bf2f((unsigned short)v[2 * w]),     0.f),
                    fmaxf(x1f[ks][2 * w + 1] - bf2f((unsigned short)v[2 * w + 1]), 0.f));
#pragma unroll
            for (int cot = 0; cot < 4; cot++)
                acc1[cot] = __builtin_amdgcn_mfma_f32_16x16x32_bf16(af1[cot][ks], bb.v, acc1[cot], 0, 0, 0);
        }
#pragma unroll
        for (int cot = 0; cot < 4; cot++) {
            f32x4 wa = *(const f32x4*)(ws + OFF_W64 + cot * 16 + q * 4);
            f32x4 wb = *(const f32x4*)(ws + OFF_W65 + cot * 16 + q * 4);
            f32x4 cc = *(const f32x4*)(ws + OFF_C1V + cot * 16 + q * 4);
            float t[4];
#pragma unroll
            for (int r = 0; r < 4; r++)
                t[r] = fmaxf(acc1[cot][r] + wa[r] * s64v[ct] + wb[r] * s65v[ct] + cc[r], 0.f);
            uint2 pk;
            pk.x = pk2bf(t[0], t[1]);
            pk.y = pk2bf(t[2], t[3]);
            int byte = col * 128 + cot * 32 + q * 8;
            *(uint2*)(t1p + SWZ(byte)) = pk;
        }
    }

    // GEMM2 (swapped: D[k][g]) + softmax over k
    unsigned held[4][4][2];
#pragma unroll
    for (int gt = 0; gt < 4; gt++) {
        f32x4 acc2[4];
#pragma unroll
        for (int kt = 0; kt < 4; kt++) acc2[kt] = (f32x4)0.f;
#pragma unroll
        for (int kt = 0; kt < 4; kt++) {
#pragma unroll
            for (int ks2 = 0; ks2 < 2; ks2++) {
                int byte = (lidx + 16 * kt) * 128 + ks2 * 64 + q * 16;
                s16x8 a = *(const s16x8*)(t1p + SWZ(byte));
                acc2[kt] = __builtin_amdgcn_mfma_f32_16x16x32_bf16(a, af2[gt][ks2], acc2[kt], 0, 0, 0);
            }
        }
        float mx = -1e30f;
#pragma unroll
        for (int kt = 0; kt < 3; kt++)
#pragma unroll
            for (int r = 0; r < 4; r++) mx = fmaxf(mx, acc2[kt][r]);
        if (q == 0) mx = fmaxf(mx, acc2[3][0]);
        mx = fmaxf(mx, __shfl_xor(mx, 16));
        mx = fmaxf(mx, __shfl_xor(mx, 32));
        float e[4][4];
        float sum = 0.f;
#pragma unroll
        for (int kt = 0; kt < 4; kt++)
#pragma unroll
            for (int r = 0; r < 4; r++) {
                bool valid = (kt < 3) || (q == 0 && r == 0);
                float ev = valid ? exp2f((acc2[kt][r] - mx) * 1.44269504f) : 0.f;
                e[kt][r] = ev;
                sum += ev;
            }
        sum += __shfl_xor(sum, 16);
        sum += __shfl_xor(sum, 32);
        float inv = 1.f / sum;
#pragma unroll
        for (int kt = 0; kt < 4; kt++) {
            held[gt][kt][0] = pk2bf(e[kt][0] * inv, e[kt][1] * inv);
            held[gt][kt][1] = pk2bf(e[kt][2] * inv, e[kt][3] * inv);
        }
    }

    // overwrite t1 buffer with wgt [g][k] bf16 (byte = g*128 + 2k, swizzled)
#pragma unroll
    for (int gt = 0; gt < 4; gt++)
#pragma unroll
        for (int kt = 0; kt < 4; kt++) {
            int byte = (lidx + 16 * gt) * 128 + kt * 32 + q * 8;
            uint2 pk;
            pk.x = held[gt][kt][0];
            pk.y = held[gt][kt][1];
            *(uint2*)(t1p + SWZ(byte)) = pk;
        }

    // aggregation: ROLLED loop (code-size experiment). Per-k: nb from LDS,
    // w from LDS u16 at SWZ(lane*128 + 2k), x3 row gather, 8 fma.
    f32x4 a30 = (f32x4)0.f, a31 = (f32x4)0.f;
    const unsigned short* x3b = x3t + (size_t)b * HWTOT * 512 + lane * 8;
#pragma unroll 7
    for (int k = 0; k < KKW; k++) {
        int nb = nbo[k];
        float w = bf2f(*(const unsigned short*)(t1p + SWZ(lane * 128 + k * 2)));
        s16x8 v = *(const s16x8*)(x3b + (size_t)nb * 512);
#pragma unroll
        for (int r = 0; r < 4; r++) {
            a30[r] = fmaf(w, bf2f((unsigned short)v[r]), a30[r]);
            a31[r] = fmaf(w, bf2f((unsigned short)v[4 + r]), a31[r]);
        }
    }
    float* ob = out + ((size_t)b * COUT + lane * 8) * HWTOT + n;
#pragma unroll
    for (int i = 0; i < 4; i++) ob[i * HWTOT] = a30[i];
#pragma unroll
    for (int i = 0; i < 4; i++) ob[(i + 4) * HWTOT] = a31[i];
}

extern "C" void kernel_launch(void* const* d_in, const int* in_sizes, int n_in,
                              void* d_out, int out_size, void* d_ws, size_t ws_size,
                              hipStream_t stream) {
    const float* x = (const float*)d_in[0];
    const float* w1 = (const float*)d_in[1];
    const float* b1 = (const float*)d_in[2];
    const float* w2 = (const float*)d_in[3];
    const float* b2 = (const float*)d_in[4];
    const float* w3 = (const float*)d_in[5];
    const float* b3 = (const float*)d_in[6];
    const float* wp = (const float*)d_in[7];
    const float* bp = (const float*)d_in[8];
    const float* g0 = (const float*)d_in[9];
    const float* be0 = (const float*)d_in[10];
    const float* m0 = (const float*)d_in[11];
    const float* v0 = (const float*)d_in[12];
    const float* wcw1 = (const float*)d_in[13];
    const float* g1 = (const float*)d_in[14];
    const float* be1 = (const float*)d_in[15];
    const float* m1 = (const float*)d_in[16];
    const float* v1 = (const float*)d_in[17];
    const float* wcw2 = (const float*)d_in[18];
    float* ws = (float*)d_ws;
    float* out = (float*)d_out;

    if (ws_size >= WS_NEED_FLOATS * 4ull) {
        k_prep<<<297, 256, 0, stream>>>(x, w1, w2, w3, wp, bp, g0, be0, m0, v0,
                                        wcw1, g1, be1, m1, v1, wcw2, ws);
        k_projm<<<dim3(10, 16, 4), 256, 0, stream>>>(b1, b2, b3, ws);
    } else {
        k_setup<<<1, 256, 0, stream>>>(wp, bp, g0, be0, m0, v0, wcw1, g1, be1, m1, v1, wcw2, ws);
        k_proj<<<dim3(16, 10, 4), 256, 0, stream>>>(x, w1, b1, w2, b2, w3, b3, ws);
    }
    k_fused<<<4096, 64, 0, stream>>>(ws, out);
}